// Round 5
// baseline (560.865 us; speedup 1.0000x reference)
//
#include <hip/hip_runtime.h>
#include <math.h>

// Problem constants (B, L, D, H from the reference)
constexpr int Bsz = 4;
constexpr int Lsz = 2048;
constexpr int Dsz = 1024;
constexpr int Hn  = 8;
constexpr int Dh  = 128;   // Dsz / Hn
constexpr int GM  = Bsz * Lsz;   // 8192
constexpr int GK  = Dsz;         // 1024 (K dim of every projection GEMM)

typedef __attribute__((ext_vector_type(8))) short bf16x8;
typedef __attribute__((ext_vector_type(4))) float f32x4;

union FragU { unsigned int u[4]; bf16x8 f; };

// async global->LDS, 16B per lane (wave-uniform base + lane*16 dest)
__device__ __forceinline__ void gload16(const void* g, void* l) {
    __builtin_amdgcn_global_load_lds(
        (const __attribute__((address_space(1))) unsigned int*)g,
        (__attribute__((address_space(3))) unsigned int*)l, 16, 0, 0);
}

// ---------------------------------------------------------------------------
// fp32 -> bf16 hi/lo split (hi = truncate, lo = truncated residual).
// ---------------------------------------------------------------------------
__device__ __forceinline__ void split4(float4 f, ushort4& h, ushort4& l2) {
    unsigned int ux = __float_as_uint(f.x), uy = __float_as_uint(f.y),
                 uz = __float_as_uint(f.z), uw = __float_as_uint(f.w);
    h.x = (unsigned short)(ux >> 16); h.y = (unsigned short)(uy >> 16);
    h.z = (unsigned short)(uz >> 16); h.w = (unsigned short)(uw >> 16);
    float lx = f.x - __uint_as_float(ux & 0xffff0000u);
    float ly = f.y - __uint_as_float(uy & 0xffff0000u);
    float lz = f.z - __uint_as_float(uz & 0xffff0000u);
    float lw = f.w - __uint_as_float(uw & 0xffff0000u);
    l2.x = (unsigned short)(__float_as_uint(lx) >> 16);
    l2.y = (unsigned short)(__float_as_uint(ly) >> 16);
    l2.z = (unsigned short)(__float_as_uint(lz) >> 16);
    l2.w = (unsigned short)(__float_as_uint(lw) >> 16);
}

struct WConv4 {
    const float4* w[4];
    ushort4* h[4];
    ushort4* l[4];
    float s[4];
};

// 4 weights in one launch: 1024 blocks per weight (WD/4/256 = 1024)
__global__ __launch_bounds__(256) void conv_w4(WConv4 a) {
    int wi = blockIdx.x >> 10;
    int i = (blockIdx.x & 1023) * 256 + threadIdx.x;
    float4 f = a.w[wi][i];
    float s = a.s[wi];
    f.x *= s; f.y *= s; f.z *= s; f.w *= s;
    ushort4 h, l;
    split4(f, h, l);
    a.h[wi][i] = h; a.l[wi][i] = l;
}

__global__ __launch_bounds__(256) void conv_in(const float4* __restrict__ src,
                                               ushort4* __restrict__ hi,
                                               ushort4* __restrict__ lo) {
    int i = blockIdx.x * 256 + threadIdx.x;   // MD/4 = 2097152 elems
    ushort4 h, l;
    split4(src[i], h, l);
    hi[i] = h; lo[i] = l;
}

// ---------------------------------------------------------------------------
// All-bf16 split GEMM, 3-product (Ah*Bh + Ah*Bl + Al*Bh), fp32-accurate.
// 128x64 tile, BK=32, 256 thr = 4 waves; wave quadrant 64x32 (4x2 frags of
// 16x16x32 MFMA). Grid: (N/64, 64). Row-tiles entirely >= slen[batch] skip.
//   MODE 0: fp32 C row-major (O-proj; skipped tiles write zeros)
//   MODE 1: bf16 hi/lo row-major (Q-proj)
//   MODE 2: fused KV, N=2048: cols <1024 -> K row-major hi/lo; cols >=1024 ->
//           V transposed (Ct[n][m]) hi/lo
// ---------------------------------------------------------------------------
template<int MODE>
__global__ __launch_bounds__(256) void gemm_bb(
    const ushort* __restrict__ Ahi, const ushort* __restrict__ Alo,
    const ushort* __restrict__ Bhi, const ushort* __restrict__ Blo,
    float* __restrict__ C,
    ushort* __restrict__ Chi, ushort* __restrict__ Clo,
    ushort* __restrict__ C2hi, ushort* __restrict__ C2lo,
    const int* __restrict__ slen)
{
    const int tid = threadIdx.x;
    const int bm = blockIdx.y << 7;
    const int bn = blockIdx.x << 6;

    // ---- masked-row tile skip ----
    const int nk = slen[bm >> 11];          // batch = row / Lsz
    if ((bm & (Lsz - 1)) >= nk) {
        if (MODE == 0) {
            int row = tid >> 1;             // 0..127
            int cb  = (tid & 1) << 5;       // 0,32
            float4 z = make_float4(0.f, 0.f, 0.f, 0.f);
            float4* cp = (float4*)(C + (size_t)(bm + row) * Dsz + bn + cb);
#pragma unroll
            for (int i = 0; i < 8; ++i) cp[i] = z;
        }
        return;
    }

    __shared__ ushort Ah_s[128 * 32];   // 8 KB each
    __shared__ ushort Al_s[128 * 32];
    __shared__ ushort Bh_s[64 * 32];    // 4 KB each
    __shared__ ushort Bl_s[64 * 32];

    const int w  = tid >> 6;
    const int l  = tid & 63;
    const int wm = w & 1;               // 64-row half
    const int wn = w >> 1;              // 32-col half

    // staging decode: chunk slot s(16B): row=(s>>6)*16+(s&15), k=((s>>4)&3)*8
    const ushort* agh[2]; const ushort* agl[2]; ushort* alh[2]; ushort* all2[2];
#pragma unroll
    for (int i = 0; i < 2; ++i) {
        int s = i * 256 + tid;                 // 0..511 (128 rows)
        int row = ((s >> 6) << 4) + (s & 15);
        int kk  = ((s >> 4) & 3) << 3;
        agh[i] = Ahi + (size_t)(bm + row) * GK + kk;
        agl[i] = Alo + (size_t)(bm + row) * GK + kk;
        alh[i] = &Ah_s[s * 8];  all2[i] = &Al_s[s * 8];
    }
    const ushort* bgh; const ushort* bgl; ushort* blh; ushort* bll;
    {
        int s = tid;                           // 0..255 (64 rows)
        int row = ((s >> 6) << 4) + (s & 15);
        int kk  = ((s >> 4) & 3) << 3;
        bgh = Bhi + (size_t)(bn + row) * GK + kk;
        bgl = Blo + (size_t)(bn + row) * GK + kk;
        blh = &Bh_s[s * 8];  bll = &Bl_s[s * 8];
    }

    f32x4 acc[4][2];
#pragma unroll
    for (int i = 0; i < 4; ++i) { acc[i][0] = (f32x4)0.f; acc[i][1] = (f32x4)0.f; }

    for (int k0 = 0; k0 < GK; k0 += 32) {
#pragma unroll
        for (int i = 0; i < 2; ++i) {
            gload16(agh[i] + k0, alh[i]);
            gload16(agl[i] + k0, all2[i]);
        }
        gload16(bgh + k0, blh);
        gload16(bgl + k0, bll);
        __syncthreads();

        bf16x8 ah[4], al4[4], bh2[2], bl2[2];
#pragma unroll
        for (int f = 0; f < 4; ++f) {
            int fmg = wm * 4 + f;
            ah[f]  = *(const bf16x8*)&Ah_s[(fmg * 64 + l) * 8];
            al4[f] = *(const bf16x8*)&Al_s[(fmg * 64 + l) * 8];
        }
#pragma unroll
        for (int f = 0; f < 2; ++f) {
            int fng = wn * 2 + f;
            bh2[f] = *(const bf16x8*)&Bh_s[(fng * 64 + l) * 8];
            bl2[f] = *(const bf16x8*)&Bl_s[(fng * 64 + l) * 8];
        }

#pragma unroll
        for (int fm = 0; fm < 4; ++fm)
#pragma unroll
            for (int fn = 0; fn < 2; ++fn) {
                acc[fm][fn] = __builtin_amdgcn_mfma_f32_16x16x32_bf16(
                    ah[fm], bh2[fn], acc[fm][fn], 0, 0, 0);
                acc[fm][fn] = __builtin_amdgcn_mfma_f32_16x16x32_bf16(
                    ah[fm], bl2[fn], acc[fm][fn], 0, 0, 0);
                acc[fm][fn] = __builtin_amdgcn_mfma_f32_16x16x32_bf16(
                    al4[fm], bh2[fn], acc[fm][fn], 0, 0, 0);
            }
        __syncthreads();
    }

    // epilogue: C/D layout row=(l>>4)*4+reg, col=l&15 (m89-verified)
    const int rq = (l >> 4) << 2;
    const int cq = l & 15;
#pragma unroll
    for (int fm = 0; fm < 4; ++fm) {
        int r0 = bm + wm * 64 + fm * 16 + rq;
#pragma unroll
        for (int fn = 0; fn < 2; ++fn) {
            int c0 = bn + wn * 32 + fn * 16 + cq;
            if (MODE == 0) {
#pragma unroll
                for (int r = 0; r < 4; ++r)
                    C[(size_t)(r0 + r) * Dsz + c0] = acc[fm][fn][r];
            } else if (MODE == 1) {
#pragma unroll
                for (int r = 0; r < 4; ++r) {
                    float f = acc[fm][fn][r];
                    unsigned int u = __float_as_uint(f);
                    float res = f - __uint_as_float(u & 0xffff0000u);
                    Chi[(size_t)(r0 + r) * Dsz + c0] = (unsigned short)(u >> 16);
                    Clo[(size_t)(r0 + r) * Dsz + c0] =
                        (unsigned short)(__float_as_uint(res) >> 16);
                }
            } else {
                if (c0 < Dsz) {   // K output, row-major (uniform per fn)
#pragma unroll
                    for (int r = 0; r < 4; ++r) {
                        float f = acc[fm][fn][r];
                        unsigned int u = __float_as_uint(f);
                        float res = f - __uint_as_float(u & 0xffff0000u);
                        Chi[(size_t)(r0 + r) * Dsz + c0] = (unsigned short)(u >> 16);
                        Clo[(size_t)(r0 + r) * Dsz + c0] =
                            (unsigned short)(__float_as_uint(res) >> 16);
                    }
                } else {          // V output, transposed
                    ushort4 h4, l4;
                    unsigned short* hp = (unsigned short*)&h4;
                    unsigned short* lp = (unsigned short*)&l4;
#pragma unroll
                    for (int r = 0; r < 4; ++r) {
                        float f = acc[fm][fn][r];
                        unsigned int u = __float_as_uint(f);
                        float res = f - __uint_as_float(u & 0xffff0000u);
                        hp[r] = (unsigned short)(u >> 16);
                        lp[r] = (unsigned short)(__float_as_uint(res) >> 16);
                    }
                    *(ushort4*)&C2hi[(size_t)(c0 - Dsz) * GM + r0] = h4;
                    *(ushort4*)&C2lo[(size_t)(c0 - Dsz) * GM + r0] = l4;
                }
            }
        }
    }
}

// ---------------------------------------------------------------------------
// MFMA flash attention, split-bf16, max-free online softmax.
// NOW double-buffered: K/V tile t+1 prefetched via global_load_lds right
// after the single per-iter barrier; the barrier's vmcnt(0) drain waits on
// loads issued a full compute-iteration earlier (nearly free).
// ---------------------------------------------------------------------------
__global__ __launch_bounds__(256) void flash_mfma(
    const ushort* __restrict__ Qhi, const ushort* __restrict__ Qlo,
    const ushort* __restrict__ Khi, const ushort* __restrict__ Klo,
    const ushort* __restrict__ Vthi, const ushort* __restrict__ Vtlo,
    const int* __restrict__ slen,
    ushort* __restrict__ Ohi, ushort* __restrict__ Olo)
{
    __shared__ __align__(16) ushort Ks[2][32 * 256];      // 2 x 16 KB
    __shared__ __align__(16) ushort Vs[2][128 * 64];      // 2 x 16 KB
    __shared__ __align__(16) unsigned int Pb[4 * 16 * 36];  // 9 KB

    const int tid = threadIdx.x;
    const int w = tid >> 6, l = tid & 63;
    const int lg = l >> 4, lc = l & 15;
    const int q0 = blockIdx.x << 6;
    const int h = blockIdx.y, b = blockIdx.z;
    const int nk = slen[b];

    if (q0 >= nk) {   // fully-masked q-tile: exact zeros
        const int r = tid >> 2, c0 = (tid & 3) << 5;
        size_t base = (size_t)(b * Lsz + q0 + r) * Dsz + h * Dh + c0;
        uint4 z = make_uint4(0u, 0u, 0u, 0u);
#pragma unroll
        for (int i = 0; i < 4; ++i) {
            *(uint4*)&Ohi[base + i * 8] = z;
            *(uint4*)&Olo[base + i * 8] = z;
        }
        return;
    }

    // ---- Q strip -> A-frags (pre-split bf16), once per block ----
    bf16x8 qh[4], ql[4];
    {
        size_t base = (size_t)(b * Lsz + q0 + (w << 4) + lc) * Dsz + h * Dh + lg * 8;
#pragma unroll
        for (int s = 0; s < 4; ++s) {
            qh[s] = *(const bf16x8*)&Qhi[base + s * 32];
            ql[s] = *(const bf16x8*)&Qlo[base + s * 32];
        }
    }

    // ---- staging decode (physical chunk slot -> global source) ----
    const ushort* ksrc[4]; int klds[4];
    const ushort* vsrc[4]; int vlds[4];
#pragma unroll
    for (int i = 0; i < 4; ++i) {
        int s = i * 256 + tid;              // K chunk: row j (32ch: 16 hi + 16 lo)
        int j = s >> 5, p = s & 31;
        int lg4 = (p & 15) ^ (j & 15);
        const ushort* base = (p & 16) ? Klo : Khi;
        ksrc[i] = base + (size_t)(b * Lsz + j) * Dsz + h * Dh + lg4 * 8;
        klds[i] = s * 8;
    }
#pragma unroll
    for (int i = 0; i < 4; ++i) {
        int s = i * 256 + tid;              // Vt chunk: row d (8ch: 4 hi + 4 lo)
        int d = s >> 3, p = s & 7;
        int lgc = p ^ (d & 7);
        const ushort* base = (lgc & 4) ? Vtlo : Vthi;
        vsrc[i] = base + (size_t)(h * Dh + d) * (Bsz * Lsz) + b * Lsz + (lgc & 3) * 8;
        vlds[i] = s * 8;
    }

    f32x4 oacc[8];
#pragma unroll
    for (int fd = 0; fd < 8; ++fd) oacc[fd] = (f32x4)0.f;
    float lsum[4] = {0.f, 0.f, 0.f, 0.f};
    const int pbase = w * (16 * 36);

    // ---- prefetch tile 0 ----
#pragma unroll
    for (int i = 0; i < 4; ++i) gload16(ksrc[i], &Ks[0][klds[i]]);
#pragma unroll
    for (int i = 0; i < 4; ++i) gload16(vsrc[i], &Vs[0][vlds[i]]);

    const int nt = (nk + 31) >> 5;
    for (int t = 0; t < nt; ++t) {
        __syncthreads();   // tile t resident; buffer (t+1)&1 free (read in t-1)

        if (t + 1 < nt) {  // prefetch tile t+1 (wave-uniform branch)
            const int kb2 = (t + 1) << 5;
            const int nb = (t + 1) & 1;
#pragma unroll
            for (int i = 0; i < 4; ++i)
                gload16(ksrc[i] + (size_t)kb2 * Dsz, &Ks[nb][klds[i]]);
#pragma unroll
            for (int i = 0; i < 4; ++i)
                gload16(vsrc[i] + kb2, &Vs[nb][vlds[i]]);
        }

        const ushort* Kc = Ks[t & 1];
        const ushort* Vc = Vs[t & 1];
        const int kb = t << 5;

        // ---- S = Q K^T (16x32 per wave) ----
        f32x4 sa[2] = {(f32x4)0.f, (f32x4)0.f};
#pragma unroll
        for (int fn = 0; fn < 2; ++fn) {
            int j = fn * 16 + lc;
            int ro = j * 256;
#pragma unroll
            for (int s = 0; s < 4; ++s) {
                int phys = (s * 4 + lg) ^ (j & 15);
                bf16x8 kh = *(const bf16x8*)&Kc[ro + phys * 8];
                bf16x8 kl = *(const bf16x8*)&Kc[ro + 128 + phys * 8];
                sa[fn] = __builtin_amdgcn_mfma_f32_16x16x32_bf16(qh[s], kh, sa[fn], 0, 0, 0);
                sa[fn] = __builtin_amdgcn_mfma_f32_16x16x32_bf16(qh[s], kl, sa[fn], 0, 0, 0);
                sa[fn] = __builtin_amdgcn_mfma_f32_16x16x32_bf16(ql[s], kh, sa[fn], 0, 0, 0);
            }
        }

        // ---- mask tail keys (last tile only; wave-uniform branch) ----
        if (kb + 32 > nk) {
#pragma unroll
            for (int fn = 0; fn < 2; ++fn) {
                bool oob = (kb + fn * 16 + lc) >= nk;
#pragma unroll
                for (int rr = 0; rr < 4; ++rr)
                    sa[fn][rr] = oob ? -1e30f : sa[fn][rr];
            }
        }

        // ---- exp (max-free), accumulate row sums, split+pack P to LDS ----
#pragma unroll
        for (int fn = 0; fn < 2; ++fn)
#pragma unroll
            for (int rr = 0; rr < 4; ++rr) {
                float p = __expf(sa[fn][rr]);
                lsum[rr] += p;
                unsigned int u = __float_as_uint(p);
                float res = p - __uint_as_float(u & 0xffff0000u);
                unsigned int lo16 = __float_as_uint(res) >> 16;
                Pb[pbase + (lg * 4 + rr) * 36 + fn * 16 + lc] =
                    (lo16 << 16) | (u >> 16);
            }

        // ---- P: LDS -> A-frags (intra-wave region; no barrier needed) ----
        const unsigned int* pr = &Pb[pbase + lc * 36 + lg * 8];
        uint4 a0 = *(const uint4*)pr;
        uint4 a1 = *(const uint4*)(pr + 4);
        FragU PH, PL;
        PH.u[0] = (a0.x & 0xffffu) | (a0.y << 16);
        PH.u[1] = (a0.z & 0xffffu) | (a0.w << 16);
        PH.u[2] = (a1.x & 0xffffu) | (a1.y << 16);
        PH.u[3] = (a1.z & 0xffffu) | (a1.w << 16);
        PL.u[0] = (a0.x >> 16) | (a0.y & 0xffff0000u);
        PL.u[1] = (a0.z >> 16) | (a0.w & 0xffff0000u);
        PL.u[2] = (a1.x >> 16) | (a1.y & 0xffff0000u);
        PL.u[3] = (a1.z >> 16) | (a1.w & 0xffff0000u);

        // ---- O += P V (16x128 per wave) ----
#pragma unroll
        for (int fd = 0; fd < 8; ++fd) {
            int d = fd * 16 + lc;
            int ro = d * 64;
            int ph = lg ^ (d & 7);
            int pl2 = (4 + lg) ^ (d & 7);
            bf16x8 vh = *(const bf16x8*)&Vc[ro + ph * 8];
            bf16x8 vl = *(const bf16x8*)&Vc[ro + pl2 * 8];
            oacc[fd] = __builtin_amdgcn_mfma_f32_16x16x32_bf16(PH.f, vh, oacc[fd], 0, 0, 0);
            oacc[fd] = __builtin_amdgcn_mfma_f32_16x16x32_bf16(PH.f, vl, oacc[fd], 0, 0, 0);
            oacc[fd] = __builtin_amdgcn_mfma_f32_16x16x32_bf16(PL.f, vh, oacc[fd], 0, 0, 0);
        }
    }

    // ---- reduce row sums across the 16 lanes of each quad group ----
#pragma unroll
    for (int m = 1; m < 16; m <<= 1)
#pragma unroll
        for (int rr = 0; rr < 4; ++rr)
            lsum[rr] += __shfl_xor(lsum[rr], m, 64);

    // ---- normalize, query-mask, split, store (in-place over Qhi/Qlo) ----
#pragma unroll
    for (int rr = 0; rr < 4; ++rr) {
        int q = q0 + (w << 4) + (lg << 2) + rr;
        bool valid = q < nk;
        float inv = valid ? (1.f / lsum[rr]) : 0.f;
        size_t base = (size_t)(b * Lsz + q) * Dsz + h * Dh + lc;
#pragma unroll
        for (int fd = 0; fd < 8; ++fd) {
            float val = valid ? oacc[fd][rr] * inv : 0.f;
            unsigned int u = __float_as_uint(val);
            float res = val - __uint_as_float(u & 0xffff0000u);
            Ohi[base + fd * 16] = (unsigned short)(u >> 16);
            Olo[base + fd * 16] = (unsigned short)(__float_as_uint(res) >> 16);
        }
    }
}

// ---------------------------------------------------------------------------
// ws: Qhi|Qlo|Khi|Klo|Vthi|Vtlo (6 x MD) + Wqh|Wql (2 x WD) + Wkvh|Wkvl
// (2 x 2WD) + Woh|Wol (2 x WD) = 6 MD + 8 WD ushort = 117.4 MB.
// Input splits (queries/keys) use d_out as scratch; final GEMM overwrites it.
// ---------------------------------------------------------------------------
extern "C" void kernel_launch(void* const* d_in, const int* in_sizes, int n_in,
                              void* d_out, int out_size, void* d_ws, size_t ws_size,
                              hipStream_t stream) {
    (void)in_sizes; (void)n_in; (void)out_size; (void)ws_size;
    const float* queries = (const float*)d_in[0];
    const float* keys    = (const float*)d_in[1];
    const int*   slen    = (const int*)d_in[2];
    const float* Wq      = (const float*)d_in[3];
    const float* Wk      = (const float*)d_in[4];
    const float* Wv      = (const float*)d_in[5];
    const float* Wo      = (const float*)d_in[6];
    float* out = (float*)d_out;

    const size_t MD = (size_t)Bsz * Lsz * Dsz;   // 8388608
    const size_t WD = (size_t)Dsz * Dsz;         // 1048576
    ushort* Qhi  = (ushort*)d_ws;
    ushort* Qlo  = Qhi + MD;
    ushort* Khi  = Qlo + MD;
    ushort* Klo  = Khi + MD;
    ushort* Vthi = Klo + MD;
    ushort* Vtlo = Vthi + MD;
    ushort* Wqh  = Vtlo + MD;
    ushort* Wql  = Wqh + WD;
    ushort* Wkvh = Wql + WD;       // rows 0..1023 = Wk, rows 1024..2047 = Wv
    ushort* Wkvl = Wkvh + 2 * WD;
    ushort* Woh  = Wkvl + 2 * WD;
    ushort* Wol  = Woh + WD;

    // input splits live in d_out (scratch until the final GEMM rewrites it)
    ushort* Xhi = (ushort*)d_out;
    ushort* Xlo = Xhi + MD;

    const float scaleQ = 0.08838834764831845f;   // 1/sqrt(Dh), folded into Wq
    WConv4 wa;
    wa.w[0] = (const float4*)Wq; wa.h[0] = (ushort4*)Wqh;        wa.l[0] = (ushort4*)Wql;        wa.s[0] = scaleQ;
    wa.w[1] = (const float4*)Wk; wa.h[1] = (ushort4*)Wkvh;       wa.l[1] = (ushort4*)Wkvl;       wa.s[1] = 1.f;
    wa.w[2] = (const float4*)Wv; wa.h[2] = (ushort4*)(Wkvh + WD); wa.l[2] = (ushort4*)(Wkvl + WD); wa.s[2] = 1.f;
    wa.w[3] = (const float4*)Wo; wa.h[3] = (ushort4*)Woh;        wa.l[3] = (ushort4*)Wol;        wa.s[3] = 1.f;
    conv_w4<<<4096, 256, 0, stream>>>(wa);

    const int nblk_in = (int)(MD / 4 / 256);     // 8192

    // queries -> split -> Q projection
    conv_in<<<nblk_in, 256, 0, stream>>>((const float4*)queries, (ushort4*)Xhi, (ushort4*)Xlo);
    gemm_bb<1><<<dim3(16, 64), 256, 0, stream>>>(
        Xhi, Xlo, Wqh, Wql, nullptr, Qhi, Qlo, nullptr, nullptr, slen);

    // keys -> split -> fused K + V projection (N = 2048)
    conv_in<<<nblk_in, 256, 0, stream>>>((const float4*)keys, (ushort4*)Xhi, (ushort4*)Xlo);
    gemm_bb<2><<<dim3(32, 64), 256, 0, stream>>>(
        Xhi, Xlo, Wkvh, Wkvl, nullptr, Khi, Klo, Vthi, Vtlo, slen);

    dim3 ga(Lsz / 64, Hn, Bsz);       // (32, 8, 4)
    flash_mfma<<<ga, 256, 0, stream>>>(Qhi, Qlo, Khi, Klo, Vthi, Vtlo, slen,
                                       Qhi, Qlo /* O in-place */);

    // output projection (reads pre-split O, writes fp32 out; masked tiles zero)
    gemm_bb<0><<<dim3(16, 64), 256, 0, stream>>>(
        Qhi, Qlo, Woh, Wol, out, nullptr, nullptr, nullptr, nullptr, slen);
}

// Round 6
// 430.995 us; speedup vs baseline: 1.3013x; 1.3013x over previous
//
#include <hip/hip_runtime.h>
#include <math.h>

// Problem constants (B, L, D, H from the reference)
constexpr int Bsz = 4;
constexpr int Lsz = 2048;
constexpr int Dsz = 1024;
constexpr int Hn  = 8;
constexpr int Dh  = 128;   // Dsz / Hn
constexpr int GM  = Bsz * Lsz;   // 8192
constexpr int GK  = Dsz;         // 1024 (K dim of every projection GEMM)

typedef __attribute__((ext_vector_type(8))) short bf16x8;
typedef __attribute__((ext_vector_type(4))) float f32x4;

union FragU { unsigned int u[4]; bf16x8 f; };

// async global->LDS, 16B per lane (wave-uniform base + lane*16 dest)
__device__ __forceinline__ void gload16(const void* g, void* l) {
    __builtin_amdgcn_global_load_lds(
        (const __attribute__((address_space(1))) unsigned int*)g,
        (__attribute__((address_space(3))) unsigned int*)l, 16, 0, 0);
}

// split two fp32 into packed bf16 hi-pair / lo-pair (hi=truncate, lo=residual)
__device__ __forceinline__ void split2(float f0, float f1,
                                       unsigned int& hp, unsigned int& lp) {
    unsigned int u0 = __float_as_uint(f0), u1 = __float_as_uint(f1);
    hp = (u0 >> 16) | (u1 & 0xffff0000u);
    float l0 = f0 - __uint_as_float(u0 & 0xffff0000u);
    float l1 = f1 - __uint_as_float(u1 & 0xffff0000u);
    lp = (__float_as_uint(l0) >> 16) | (__float_as_uint(l1) & 0xffff0000u);
}

__device__ __forceinline__ void split4(float4 f, ushort4& h, ushort4& l2) {
    unsigned int ux = __float_as_uint(f.x), uy = __float_as_uint(f.y),
                 uz = __float_as_uint(f.z), uw = __float_as_uint(f.w);
    h.x = (unsigned short)(ux >> 16); h.y = (unsigned short)(uy >> 16);
    h.z = (unsigned short)(uz >> 16); h.w = (unsigned short)(uw >> 16);
    float lx = f.x - __uint_as_float(ux & 0xffff0000u);
    float ly = f.y - __uint_as_float(uy & 0xffff0000u);
    float lz = f.z - __uint_as_float(uz & 0xffff0000u);
    float lw = f.w - __uint_as_float(uw & 0xffff0000u);
    l2.x = (unsigned short)(__float_as_uint(lx) >> 16);
    l2.y = (unsigned short)(__float_as_uint(ly) >> 16);
    l2.z = (unsigned short)(__float_as_uint(lz) >> 16);
    l2.w = (unsigned short)(__float_as_uint(lw) >> 16);
}

struct WConv4 {
    const float4* w[4];
    ushort4* h[4];
    ushort4* l[4];
    float s[4];
};

// 4 weights in one launch: 1024 blocks per weight (WD/4/256 = 1024)
__global__ __launch_bounds__(256) void conv_w4(WConv4 a) {
    int wi = blockIdx.x >> 10;
    int i = (blockIdx.x & 1023) * 256 + threadIdx.x;
    float4 f = a.w[wi][i];
    float s = a.s[wi];
    f.x *= s; f.y *= s; f.z *= s; f.w *= s;
    ushort4 h, l;
    split4(f, h, l);
    a.h[wi][i] = h; a.l[wi][i] = l;
}

// ---------------------------------------------------------------------------
// Fused QKV projection GEMM. N = 3072 over fused weights [Wq*s; Wk; Wv].
// 128x128 tile, BK=32, 256 thr = 4 waves, 4x4 frags of 16x16x32 MFMA.
// A = raw fp32 (queries for cols <1024, keys otherwise), hi/lo split
// IN-REGISTER (r2-proven: zero measured cost vs pre-split — latency-bound).
// B = pre-split bf16 hi/lo. 3-product fp32-accurate accumulation.
// Outputs: cols [0,1024) -> Qhi/Qlo row-major; [1024,2048) -> Khi/Klo
// row-major; [2048,3072) -> Vthi/Vtlo TRANSPOSED.
// Row-tiles with all rows >= slen[batch] skip entirely (downstream never
// reads them: flash q/k/v reads and O-proj are 128-tile aligned).
// ---------------------------------------------------------------------------
__global__ __launch_bounds__(256) void gemm_qkv(
    const float* __restrict__ Aq, const float* __restrict__ Ak,
    const ushort* __restrict__ Wfh, const ushort* __restrict__ Wfl,
    ushort* __restrict__ Qhi, ushort* __restrict__ Qlo,
    ushort* __restrict__ Khi, ushort* __restrict__ Klo,
    ushort* __restrict__ Vthi, ushort* __restrict__ Vtlo,
    const int* __restrict__ slen)
{
    const int tid = threadIdx.x;
    const int bm = blockIdx.y << 7;
    const int bn = blockIdx.x << 7;        // 0..2944 (fused N = 3072)
    const int grp = bn >> 10;              // 0:Q 1:K 2:V

    const int nk = slen[bm >> 11];
    if ((bm & (Lsz - 1)) >= nk) return;    // skipped tile, never read downstream

    __shared__ float  As[128 * 32];        // 16 KB (fp32 A tile)
    __shared__ ushort Bh_s[128 * 32];      // 8 KB
    __shared__ ushort Bl_s[128 * 32];      // 8 KB

    const float* A = (grp == 0) ? Aq : Ak;

    const int w  = tid >> 6;
    const int l  = tid & 63;
    const int wm = w & 1;
    const int wn = w >> 1;

    // A staging decode (r2-verified): 1024 16B chunks of fp32
    const float* agp[4]; float* alp[4];
#pragma unroll
    for (int i = 0; i < 4; ++i) {
        int s = i * 256 + tid;
        int row = ((s >> 7) << 4) + (s & 15);
        int kk  = (((s >> 4) & 3) << 3) + (((s >> 6) & 1) << 2);
        agp[i] = A + (size_t)(bm + row) * GK + kk;
        alp[i] = &As[s * 4];
    }
    // B staging decode (r3-verified): 512 16B chunks each of hi/lo
    const ushort* bgh[2]; const ushort* bgl[2]; ushort* blh[2]; ushort* bll[2];
#pragma unroll
    for (int i = 0; i < 2; ++i) {
        int s = i * 256 + tid;
        int row = ((s >> 6) << 4) + (s & 15);
        int kk  = ((s >> 4) & 3) << 3;
        bgh[i] = Wfh + (size_t)(bn + row) * GK + kk;
        bgl[i] = Wfl + (size_t)(bn + row) * GK + kk;
        blh[i] = &Bh_s[s * 8];
        bll[i] = &Bl_s[s * 8];
    }

    f32x4 acc[4][4];
#pragma unroll
    for (int i = 0; i < 4; ++i)
#pragma unroll
        for (int j = 0; j < 4; ++j) acc[i][j] = (f32x4)0.f;

    for (int k0 = 0; k0 < GK; k0 += 32) {
#pragma unroll
        for (int i = 0; i < 4; ++i) gload16(agp[i] + k0, alp[i]);
#pragma unroll
        for (int i = 0; i < 2; ++i) {
            gload16(bgh[i] + k0, blh[i]);
            gload16(bgl[i] + k0, bll[i]);
        }
        __syncthreads();

        FragU ah[4], al4[4];
        bf16x8 bhf[4], blf[4];
#pragma unroll
        for (int fn = 0; fn < 4; ++fn) {
            int fng = wn * 4 + fn;
            bhf[fn] = *(const bf16x8*)&Bh_s[(fng * 64 + l) * 8];
            blf[fn] = *(const bf16x8*)&Bl_s[(fng * 64 + l) * 8];
        }
#pragma unroll
        for (int fm = 0; fm < 4; ++fm) {
            int fmg = wm * 4 + fm;
            float4 fa0 = *(const float4*)&As[(fmg * 128 + l) * 4];
            float4 fa1 = *(const float4*)&As[(fmg * 128 + 64 + l) * 4];
            split2(fa0.x, fa0.y, ah[fm].u[0], al4[fm].u[0]);
            split2(fa0.z, fa0.w, ah[fm].u[1], al4[fm].u[1]);
            split2(fa1.x, fa1.y, ah[fm].u[2], al4[fm].u[2]);
            split2(fa1.z, fa1.w, ah[fm].u[3], al4[fm].u[3]);
        }

#pragma unroll
        for (int fm = 0; fm < 4; ++fm)
#pragma unroll
            for (int fn = 0; fn < 4; ++fn) {
                acc[fm][fn] = __builtin_amdgcn_mfma_f32_16x16x32_bf16(
                    ah[fm].f, bhf[fn], acc[fm][fn], 0, 0, 0);
                acc[fm][fn] = __builtin_amdgcn_mfma_f32_16x16x32_bf16(
                    ah[fm].f, blf[fn], acc[fm][fn], 0, 0, 0);
                acc[fm][fn] = __builtin_amdgcn_mfma_f32_16x16x32_bf16(
                    al4[fm].f, bhf[fn], acc[fm][fn], 0, 0, 0);
            }
        __syncthreads();
    }

    // epilogue: C/D layout row=(l>>4)*4+reg, col=l&15 (m89-verified)
    const int rq = (l >> 4) << 2;
    const int cq = l & 15;
    ushort* OH = (grp == 0) ? Qhi : Khi;   // grp 2 handled below
    ushort* OL = (grp == 0) ? Qlo : Klo;
#pragma unroll
    for (int fm = 0; fm < 4; ++fm) {
        int r0 = bm + wm * 64 + fm * 16 + rq;
#pragma unroll
        for (int fn = 0; fn < 4; ++fn) {
            int cn = (bn & 1023) + wn * 64 + fn * 16 + cq;
            if (grp < 2) {   // Q or K: row-major hi/lo
#pragma unroll
                for (int r = 0; r < 4; ++r) {
                    float f = acc[fm][fn][r];
                    unsigned int u = __float_as_uint(f);
                    float res = f - __uint_as_float(u & 0xffff0000u);
                    OH[(size_t)(r0 + r) * Dsz + cn] = (unsigned short)(u >> 16);
                    OL[(size_t)(r0 + r) * Dsz + cn] =
                        (unsigned short)(__float_as_uint(res) >> 16);
                }
            } else {         // V: transposed hi/lo
                ushort4 h4, l4;
                unsigned short* hp = (unsigned short*)&h4;
                unsigned short* lp = (unsigned short*)&l4;
#pragma unroll
                for (int r = 0; r < 4; ++r) {
                    float f = acc[fm][fn][r];
                    unsigned int u = __float_as_uint(f);
                    float res = f - __uint_as_float(u & 0xffff0000u);
                    hp[r] = (unsigned short)(u >> 16);
                    lp[r] = (unsigned short)(__float_as_uint(res) >> 16);
                }
                *(ushort4*)&Vthi[(size_t)cn * GM + r0] = h4;
                *(ushort4*)&Vtlo[(size_t)cn * GM + r0] = l4;
            }
        }
    }
}

// ---------------------------------------------------------------------------
// O-projection GEMM: out = O @ Wo^T, fp32 result. A pre-split (flash epilogue).
// 128x128 tile, same structure. Skipped row-tiles write zeros.
// ---------------------------------------------------------------------------
__global__ __launch_bounds__(256) void gemm_o(
    const ushort* __restrict__ Ahi, const ushort* __restrict__ Alo,
    const ushort* __restrict__ Bhi, const ushort* __restrict__ Blo,
    float* __restrict__ C, const int* __restrict__ slen)
{
    const int tid = threadIdx.x;
    const int bm = blockIdx.y << 7;
    const int bn = blockIdx.x << 7;

    const int nk = slen[bm >> 11];
    if ((bm & (Lsz - 1)) >= nk) {
        int row = tid >> 1;
        int cb  = (tid & 1) << 6;
        float4 z = make_float4(0.f, 0.f, 0.f, 0.f);
        float4* cp = (float4*)(C + (size_t)(bm + row) * Dsz + bn + cb);
#pragma unroll
        for (int i = 0; i < 16; ++i) cp[i] = z;
        return;
    }

    __shared__ ushort Ah_s[128 * 32];
    __shared__ ushort Al_s[128 * 32];
    __shared__ ushort Bh_s[128 * 32];
    __shared__ ushort Bl_s[128 * 32];

    const int w  = tid >> 6;
    const int l  = tid & 63;
    const int wm = w & 1;
    const int wn = w >> 1;

    const ushort* agh[2]; const ushort* agl[2]; ushort* alh[2]; ushort* all2[2];
    const ushort* bgh[2]; const ushort* bgl[2]; ushort* blh[2]; ushort* bll[2];
#pragma unroll
    for (int i = 0; i < 2; ++i) {
        int s = i * 256 + tid;
        int row = ((s >> 6) << 4) + (s & 15);
        int kk  = ((s >> 4) & 3) << 3;
        agh[i] = Ahi + (size_t)(bm + row) * GK + kk;
        agl[i] = Alo + (size_t)(bm + row) * GK + kk;
        bgh[i] = Bhi + (size_t)(bn + row) * GK + kk;
        bgl[i] = Blo + (size_t)(bn + row) * GK + kk;
        alh[i] = &Ah_s[s * 8];  all2[i] = &Al_s[s * 8];
        blh[i] = &Bh_s[s * 8];  bll[i]  = &Bl_s[s * 8];
    }

    f32x4 acc[4][4];
#pragma unroll
    for (int i = 0; i < 4; ++i)
#pragma unroll
        for (int j = 0; j < 4; ++j) acc[i][j] = (f32x4)0.f;

    for (int k0 = 0; k0 < GK; k0 += 32) {
#pragma unroll
        for (int i = 0; i < 2; ++i) {
            gload16(agh[i] + k0, alh[i]);
            gload16(agl[i] + k0, all2[i]);
            gload16(bgh[i] + k0, blh[i]);
            gload16(bgl[i] + k0, bll[i]);
        }
        __syncthreads();

        bf16x8 ah[4], al4[4], bhf[4], blf[4];
#pragma unroll
        for (int f = 0; f < 4; ++f) {
            int fmg = wm * 4 + f;
            int fng = wn * 4 + f;
            ah[f]  = *(const bf16x8*)&Ah_s[(fmg * 64 + l) * 8];
            al4[f] = *(const bf16x8*)&Al_s[(fmg * 64 + l) * 8];
            bhf[f] = *(const bf16x8*)&Bh_s[(fng * 64 + l) * 8];
            blf[f] = *(const bf16x8*)&Bl_s[(fng * 64 + l) * 8];
        }

#pragma unroll
        for (int fm = 0; fm < 4; ++fm)
#pragma unroll
            for (int fn = 0; fn < 4; ++fn) {
                acc[fm][fn] = __builtin_amdgcn_mfma_f32_16x16x32_bf16(
                    ah[fm], bhf[fn], acc[fm][fn], 0, 0, 0);
                acc[fm][fn] = __builtin_amdgcn_mfma_f32_16x16x32_bf16(
                    ah[fm], blf[fn], acc[fm][fn], 0, 0, 0);
                acc[fm][fn] = __builtin_amdgcn_mfma_f32_16x16x32_bf16(
                    al4[fm], bhf[fn], acc[fm][fn], 0, 0, 0);
            }
        __syncthreads();
    }

    const int rq = (l >> 4) << 2;
    const int cq = l & 15;
#pragma unroll
    for (int fm = 0; fm < 4; ++fm) {
        int r0 = bm + wm * 64 + fm * 16 + rq;
#pragma unroll
        for (int fn = 0; fn < 4; ++fn) {
            int c0 = bn + wn * 64 + fn * 16 + cq;
#pragma unroll
            for (int r = 0; r < 4; ++r)
                C[(size_t)(r0 + r) * Dsz + c0] = acc[fm][fn][r];
        }
    }
}

// ---------------------------------------------------------------------------
// MFMA flash attention, split-bf16, max-free online softmax.
// BQ=128 (512 threads = 8 waves, 16 q-rows each), BK=32, SINGLE-buffered
// (r5's dbuf regressed: LDS 73 KB cut occupancy 3->2 blocks/CU).
// K/V staging serves 2x the MFMA of the BQ=64 version; barriers halved
// per q-row. Masked q-tiles return immediately (gemm_o zero-fills them).
// O written pre-split in-place over Qhi/Qlo (block reads exactly the
// 128-aligned region it writes).
// ---------------------------------------------------------------------------
__global__ __launch_bounds__(512) void flash_mfma(
    const ushort* __restrict__ Qhi, const ushort* __restrict__ Qlo,
    const ushort* __restrict__ Khi, const ushort* __restrict__ Klo,
    const ushort* __restrict__ Vthi, const ushort* __restrict__ Vtlo,
    const int* __restrict__ slen,
    ushort* __restrict__ Ohi, ushort* __restrict__ Olo)
{
    __shared__ __align__(16) ushort Ks[32 * 256];           // 16 KB
    __shared__ __align__(16) ushort Vs[128 * 64];           // 16 KB
    __shared__ __align__(16) unsigned int Pb[8 * 16 * 36];  // 18 KB

    const int tid = threadIdx.x;
    const int w = tid >> 6, l = tid & 63;
    const int lg = l >> 4, lc = l & 15;
    const int q0 = blockIdx.x << 7;        // 128-row q-tile
    const int h = blockIdx.y, b = blockIdx.z;
    const int nk = slen[b];

    if (q0 >= nk) return;   // gemm_o zero-fills these 128-aligned tiles

    // ---- Q strip -> A-frags (pre-split bf16), once per block ----
    bf16x8 qh[4], ql[4];
    {
        size_t base = (size_t)(b * Lsz + q0 + (w << 4) + lc) * Dsz + h * Dh + lg * 8;
#pragma unroll
        for (int s = 0; s < 4; ++s) {
            qh[s] = *(const bf16x8*)&Qhi[base + s * 32];
            ql[s] = *(const bf16x8*)&Qlo[base + s * 32];
        }
    }

    // ---- staging decode (512 threads, 1024 chunks each of K and Vt) ----
    const ushort* ksrc[2]; int klds[2];
    const ushort* vsrc[2]; int vlds[2];
#pragma unroll
    for (int i = 0; i < 2; ++i) {
        int s = i * 512 + tid;              // K chunk: row j (32ch: 16 hi + 16 lo)
        int j = s >> 5, p = s & 31;
        int lg4 = (p & 15) ^ (j & 15);
        const ushort* base = (p & 16) ? Klo : Khi;
        ksrc[i] = base + (size_t)(b * Lsz + j) * Dsz + h * Dh + lg4 * 8;
        klds[i] = s * 8;
    }
#pragma unroll
    for (int i = 0; i < 2; ++i) {
        int s = i * 512 + tid;              // Vt chunk: row d (8ch: 4 hi + 4 lo)
        int d = s >> 3, p = s & 7;
        int lgc = p ^ (d & 7);
        const ushort* base = (lgc & 4) ? Vtlo : Vthi;
        vsrc[i] = base + (size_t)(h * Dh + d) * (Bsz * Lsz) + b * Lsz + (lgc & 3) * 8;
        vlds[i] = s * 8;
    }

    f32x4 oacc[8];
#pragma unroll
    for (int fd = 0; fd < 8; ++fd) oacc[fd] = (f32x4)0.f;
    float lsum[4] = {0.f, 0.f, 0.f, 0.f};
    const int pbase = w * (16 * 36);

    for (int kb = 0; kb < nk; kb += 32) {
        // ---- stage K + V^T tiles ----
#pragma unroll
        for (int i = 0; i < 2; ++i) gload16(ksrc[i] + (size_t)kb * Dsz, &Ks[klds[i]]);
#pragma unroll
        for (int i = 0; i < 2; ++i) gload16(vsrc[i] + kb, &Vs[vlds[i]]);
        __syncthreads();

        // ---- S = Q K^T (16x32 per wave) ----
        f32x4 sa[2] = {(f32x4)0.f, (f32x4)0.f};
#pragma unroll
        for (int fn = 0; fn < 2; ++fn) {
            int j = fn * 16 + lc;
            int ro = j * 256;
#pragma unroll
            for (int s = 0; s < 4; ++s) {
                int phys = (s * 4 + lg) ^ (j & 15);
                bf16x8 kh = *(const bf16x8*)&Ks[ro + phys * 8];
                bf16x8 kl = *(const bf16x8*)&Ks[ro + 128 + phys * 8];
                sa[fn] = __builtin_amdgcn_mfma_f32_16x16x32_bf16(qh[s], kh, sa[fn], 0, 0, 0);
                sa[fn] = __builtin_amdgcn_mfma_f32_16x16x32_bf16(qh[s], kl, sa[fn], 0, 0, 0);
                sa[fn] = __builtin_amdgcn_mfma_f32_16x16x32_bf16(ql[s], kh, sa[fn], 0, 0, 0);
            }
        }

        // ---- mask tail keys (last tile only; wave-uniform branch) ----
        if (kb + 32 > nk) {
#pragma unroll
            for (int fn = 0; fn < 2; ++fn) {
                bool oob = (kb + fn * 16 + lc) >= nk;
#pragma unroll
                for (int rr = 0; rr < 4; ++rr)
                    sa[fn][rr] = oob ? -1e30f : sa[fn][rr];
            }
        }

        // ---- exp (max-free), accumulate row sums, split+pack P to LDS ----
#pragma unroll
        for (int fn = 0; fn < 2; ++fn)
#pragma unroll
            for (int rr = 0; rr < 4; ++rr) {
                float p = __expf(sa[fn][rr]);
                lsum[rr] += p;
                unsigned int u = __float_as_uint(p);
                float res = p - __uint_as_float(u & 0xffff0000u);
                unsigned int lo16 = __float_as_uint(res) >> 16;
                Pb[pbase + (lg * 4 + rr) * 36 + fn * 16 + lc] =
                    (lo16 << 16) | (u >> 16);
            }

        // ---- P: LDS -> A-frags (per-wave region; no barrier needed) ----
        const unsigned int* pr = &Pb[pbase + lc * 36 + lg * 8];
        uint4 a0 = *(const uint4*)pr;
        uint4 a1 = *(const uint4*)(pr + 4);
        FragU PH, PL;
        PH.u[0] = (a0.x & 0xffffu) | (a0.y << 16);
        PH.u[1] = (a0.z & 0xffffu) | (a0.w << 16);
        PH.u[2] = (a1.x & 0xffffu) | (a1.y << 16);
        PH.u[3] = (a1.z & 0xffffu) | (a1.w << 16);
        PL.u[0] = (a0.x >> 16) | (a0.y & 0xffff0000u);
        PL.u[1] = (a0.z >> 16) | (a0.w & 0xffff0000u);
        PL.u[2] = (a1.x >> 16) | (a1.y & 0xffff0000u);
        PL.u[3] = (a1.z >> 16) | (a1.w & 0xffff0000u);

        // ---- O += P V (16x128 per wave) ----
#pragma unroll
        for (int fd = 0; fd < 8; ++fd) {
            int d = fd * 16 + lc;
            int ro = d * 64;
            int ph = lg ^ (d & 7);
            int pl2 = (4 + lg) ^ (d & 7);
            bf16x8 vh = *(const bf16x8*)&Vs[ro + ph * 8];
            bf16x8 vl = *(const bf16x8*)&Vs[ro + pl2 * 8];
            oacc[fd] = __builtin_amdgcn_mfma_f32_16x16x32_bf16(PH.f, vh, oacc[fd], 0, 0, 0);
            oacc[fd] = __builtin_amdgcn_mfma_f32_16x16x32_bf16(PH.f, vl, oacc[fd], 0, 0, 0);
            oacc[fd] = __builtin_amdgcn_mfma_f32_16x16x32_bf16(PL.f, vh, oacc[fd], 0, 0, 0);
        }
        __syncthreads();   // protect Ks/Vs before next stage
    }

    // ---- reduce row sums across the 16 lanes of each quad group ----
#pragma unroll
    for (int m = 1; m < 16; m <<= 1)
#pragma unroll
        for (int rr = 0; rr < 4; ++rr)
            lsum[rr] += __shfl_xor(lsum[rr], m, 64);

    // ---- normalize, query-mask, split, store (in-place over Qhi/Qlo) ----
#pragma unroll
    for (int rr = 0; rr < 4; ++rr) {
        int q = q0 + (w << 4) + (lg << 2) + rr;
        bool valid = q < nk;
        float inv = valid ? (1.f / lsum[rr]) : 0.f;
        size_t base = (size_t)(b * Lsz + q) * Dsz + h * Dh + lc;
#pragma unroll
        for (int fd = 0; fd < 8; ++fd) {
            float val = valid ? oacc[fd][rr] * inv : 0.f;
            unsigned int u = __float_as_uint(val);
            float res = val - __uint_as_float(u & 0xffff0000u);
            Ohi[base + fd * 16] = (unsigned short)(u >> 16);
            Olo[base + fd * 16] = (unsigned short)(__float_as_uint(res) >> 16);
        }
    }
}

// ---------------------------------------------------------------------------
// ws: Qhi|Qlo|Khi|Klo|Vthi|Vtlo (6 x MD ushort) + Wfh|Wfl (fused QKV weights,
// 2 x 3WD) + Woh|Wol (2 x WD) = 6 MD + 8 WD ushort = 117.4 MB (validated).
// 4 launches total: conv_w4, gemm_qkv, flash_mfma, gemm_o.
// ---------------------------------------------------------------------------
extern "C" void kernel_launch(void* const* d_in, const int* in_sizes, int n_in,
                              void* d_out, int out_size, void* d_ws, size_t ws_size,
                              hipStream_t stream) {
    (void)in_sizes; (void)n_in; (void)out_size; (void)ws_size;
    const float* queries = (const float*)d_in[0];
    const float* keys    = (const float*)d_in[1];
    const int*   slen    = (const int*)d_in[2];
    const float* Wq      = (const float*)d_in[3];
    const float* Wk      = (const float*)d_in[4];
    const float* Wv      = (const float*)d_in[5];
    const float* Wo      = (const float*)d_in[6];
    float* out = (float*)d_out;

    const size_t MD = (size_t)Bsz * Lsz * Dsz;   // 8388608
    const size_t WD = (size_t)Dsz * Dsz;         // 1048576
    ushort* Qhi  = (ushort*)d_ws;
    ushort* Qlo  = Qhi + MD;
    ushort* Khi  = Qlo + MD;
    ushort* Klo  = Khi + MD;
    ushort* Vthi = Klo + MD;
    ushort* Vtlo = Vthi + MD;
    ushort* Wfh  = Vtlo + MD;      // fused: rows [0,1024)=Wq*s, [1024,2048)=Wk, [2048,3072)=Wv
    ushort* Wfl  = Wfh + 3 * WD;
    ushort* Woh  = Wfl + 3 * WD;
    ushort* Wol  = Woh + WD;

    const float scaleQ = 0.08838834764831845f;   // 1/sqrt(Dh), folded into Wq
    WConv4 wa;
    wa.w[0] = (const float4*)Wq; wa.h[0] = (ushort4*)Wfh;            wa.l[0] = (ushort4*)Wfl;            wa.s[0] = scaleQ;
    wa.w[1] = (const float4*)Wk; wa.h[1] = (ushort4*)(Wfh + WD);     wa.l[1] = (ushort4*)(Wfl + WD);     wa.s[1] = 1.f;
    wa.w[2] = (const float4*)Wv; wa.h[2] = (ushort4*)(Wfh + 2 * WD); wa.l[2] = (ushort4*)(Wfl + 2 * WD); wa.s[2] = 1.f;
    wa.w[3] = (const float4*)Wo; wa.h[3] = (ushort4*)Woh;            wa.l[3] = (ushort4*)Wol;            wa.s[3] = 1.f;
    conv_w4<<<4096, 256, 0, stream>>>(wa);

    // fused Q+K+V projections: N = 3072, grid (24, 64) = 1536 blocks
    gemm_qkv<<<dim3(24, 64), 256, 0, stream>>>(
        queries, keys, Wfh, Wfl, Qhi, Qlo, Khi, Klo, Vthi, Vtlo, slen);

    // flash attention: 128-row q-tiles, 512 threads
    dim3 ga(Lsz / 128, Hn, Bsz);       // (16, 8, 4)
    flash_mfma<<<ga, 512, 0, stream>>>(Qhi, Qlo, Khi, Klo, Vthi, Vtlo, slen,
                                       Qhi, Qlo /* O in-place */);

    // output projection (reads pre-split O; masked tiles -> zeros)
    gemm_o<<<dim3(8, 64), 256, 0, stream>>>(Qhi, Qlo, Woh, Wol, out, slen);
}